// Round 21
// baseline (4700.995 us; speedup 1.0000x reference)
//
#include <hip/hip_runtime.h>
#include <hip/hip_fp8.h>

typedef __bf16 bf16;
typedef __bf16 bf16x8 __attribute__((ext_vector_type(8)));
typedef __bf16 bf16x4 __attribute__((ext_vector_type(4)));
typedef float  f32x4  __attribute__((ext_vector_type(4)));

#define T_DIM 256
#define B_DIM 1024
#define HID   256
#define G4    1024
#define KIMG  784
#define KPAD  800
#define KB64  896
#define CTXD  64
#define MROWS (T_DIM*B_DIM)
#define WPITCH 264

__device__ __forceinline__ void gll16(const void* g, void* l) {
  __builtin_amdgcn_global_load_lds((const __attribute__((address_space(1))) void*)g,
                                   (__attribute__((address_space(3))) void*)l, 16, 0, 0);
}
__device__ __forceinline__ float sigm(float x) { return 1.f / (1.f + __expf(-x)); }
__device__ __forceinline__ float tanh_(float x) {
  x = fminf(fmaxf(x, -15.f), 15.f);
  float e = __expf(2.f * x);
  return (e - 1.f) / (e + 1.f);
}
__device__ __forceinline__ void bar_lds() {
  asm volatile("s_waitcnt lgkmcnt(0)\n\ts_barrier" ::: "memory");
}
__device__ __forceinline__ unsigned char to_fp8(float f) {
  __hip_fp8_e4m3 v(f);
  return *reinterpret_cast<unsigned char*>(&v);
}

// ---------------- prep kernels ----------------
// wiT[n][k], stride 896: k 0..63 = ctx weights (wi rows 789..852);
// 64..847 = img weights (wi rows 0..783); 848..895 = 0.
__global__ void k_wiT(const float* __restrict__ wi, bf16* __restrict__ wiT) {
  int n = blockIdx.x;
  for (int k = threadIdx.x; k < KB64; k += 256) {
    float v = 0.f;
    if (k < 64) v = wi[(long)(789 + k) * G4 + n];
    else if (k < 848) v = wi[(long)(k - 64) * G4 + n];
    wiT[(long)n * KB64 + k] = (bf16)v;
  }
}
__global__ void k_ext(const float* __restrict__ ctx, bf16* __restrict__ ext) {
  int idx = blockIdx.x * 256 + threadIdx.x;
  ext[idx] = (bf16)ctx[idx];
}
// fp8 e4m3 copies of ALL FOUR gate weight blocks, gate-major [g][n][k]
__global__ void k_wh8(const float* __restrict__ wh, unsigned char* __restrict__ wh8) {
  int n = blockIdx.x;
  int k = threadIdx.x;
#pragma unroll
  for (int g = 0; g < 4; ++g)
    wh8[g * 65536 + n * 256 + k] = to_fp8(wh[k * G4 + g * 256 + n]);
}
__global__ void k_W0T(const float* __restrict__ a0k, const float* __restrict__ cr0k,
                      bf16* __restrict__ w0t) {
  int n = blockIdx.x;
  int k = threadIdx.x;
  float v = (n < 32) ? a0k[k * 32 + n] : cr0k[k * 32 + (n - 32)];
  w0t[n * HID + k] = (bf16)v;
}
__global__ void k_dirgate(const float* __restrict__ wi, const float* __restrict__ emb_k,
                          const float* __restrict__ emb_b, const float* __restrict__ b_lstm,
                          float* __restrict__ dir_gate) {
  int d = blockIdx.x;
  for (int n = threadIdx.x; n < G4; n += 256) {
    float s = b_lstm[n];
#pragma unroll
    for (int j = 0; j < 5; ++j) s += (emb_k[d * 5 + j] + emb_b[j]) * wi[(KIMG + j) * G4 + n];
    dir_gate[d * G4 + n] = s;
  }
}

// ---------------- conv: thread=(row,pixel,half), acc[8] ----------------
// __launch_bounds__(256,4): 128-VGPR budget so acc[8] (~40 VGPR demand)
// stays in registers — WITHOUT this, hipcc caps at 64 VGPR for 8-wave
// occupancy and spills to scratch (R15/R20 pathology: GB-scale FETCH).
#define CONV_ROWS 8
__global__ __launch_bounds__(256, 4)
void k_conv(const float* __restrict__ img, const float* __restrict__ ck,
            const float* __restrict__ cb, bf16* __restrict__ out) {
  __shared__ float s_img[CONV_ROWS * 243];
  __shared__ float s_k[432];
  __shared__ float s_b[16];
  long r0 = (long)blockIdx.x * CONV_ROWS;
  const float* src = img + r0 * 243;
  for (int i = threadIdx.x; i < CONV_ROWS * 243; i += 256) s_img[i] = src[i];
  for (int i = threadIdx.x; i < 432; i += 256) s_k[i] = ck[i];
  if (threadIdx.x < 16) s_b[threadIdx.x] = cb[threadIdx.x];
  __syncthreads();
  // zero pad cols 784..799
  for (int i = threadIdx.x; i < CONV_ROWS * 16; i += 256) {
    int r = i >> 4, c = 784 + (i & 15);
    out[(r0 + r) * KPAD + c] = (bf16)0.f;
  }
  for (int u = threadIdx.x; u < CONV_ROWS * 98; u += 256) {
    int r = u / 98, rem = u - r * 98;
    int p = rem >> 1, half = rem & 1;
    int oy = p / 7, ox = p - oy * 7;
    const float* ib = s_img + r * 243 + (oy * 9 + ox) * 3;
    float acc[8];
#pragma unroll
    for (int ch = 0; ch < 8; ++ch) acc[ch] = s_b[half * 8 + ch];
#pragma unroll
    for (int ky = 0; ky < 3; ++ky)
#pragma unroll
      for (int kx = 0; kx < 3; ++kx)
#pragma unroll
        for (int cc = 0; cc < 3; ++cc) {
          float iv = ib[(ky * 9 + kx) * 3 + cc];
          const float* kp = s_k + ((ky * 3 + kx) * 3 + cc) * 16 + half * 8;
#pragma unroll
          for (int ch = 0; ch < 8; ++ch) acc[ch] += iv * kp[ch];
        }
    bf16x8 v;
#pragma unroll
    for (int ch = 0; ch < 8; ++ch) v[ch] = (bf16)fmaxf(acc[ch], 0.f);
    *(bf16x8*)(out + (r0 + r) * KPAD + p * 16 + half * 8) = v;
  }
}

// ---------------- big GEMM (R18 known-good): 128x128, BK=64, swizzled ----
// A-cols: [0..63]=ext(ctx, row&1023) [64..847]=conv [848..895]=junk x zeros.
__global__ __launch_bounds__(256, 2)
void k_gemm_xg(const bf16* __restrict__ A, const bf16* __restrict__ ext,
               const bf16* __restrict__ Bt, const float* __restrict__ dir_gate,
               const int* __restrict__ agent_dir, bf16* __restrict__ xg) {
  __shared__ __align__(16) bf16 As[128 * 64];
  __shared__ __align__(16) bf16 Bs[128 * 64];
  const int bid = blockIdx.x;
  const int xcd = bid & 7, local = bid >> 3;
  const long m0 = (long)(xcd * 256 + (local >> 3)) * 128;
  const int n0 = (local & 7) * 128;
  const int tid = threadIdx.x, wave = tid >> 6, lane = tid & 63;
  const int row16 = lane & 15, kq = lane >> 4, rowg = kq * 4;
  const int wr = (wave >> 1) * 64, wc = (wave & 1) * 64;

  const int srow = 8 * wave + (lane >> 3);
  const int csrc8 = ((lane & 7) ^ (lane >> 3)) * 8;   // swizzled source col (elems)
  const bf16* a_base = A + (long)(m0 + srow) * KPAD + csrc8;
  const bf16* e_base = ext + (long)((m0 & 1023) + srow) * CTXD + csrc8;
  const bf16* b_base = Bt + (long)(n0 + srow) * KB64 + csrc8;
  bf16* asd = As + wave * 512;
  bf16* bsd = Bs + wave * 512;

  f32x4 acc[4][4];
  const f32x4 zero = {0.f, 0.f, 0.f, 0.f};
#pragma unroll
  for (int i = 0; i < 4; ++i)
#pragma unroll
    for (int j = 0; j < 4; ++j) acc[i][j] = zero;

  const int swz = row16 & 7;
  for (int ks = 0; ks < 14; ++ks) {
    if (ks == 0) {
#pragma unroll
      for (int c = 0; c < 4; ++c) gll16(e_base + c * (32 * CTXD), asd + c * 2048);
    } else {
      const long ko = (long)(ks - 1) * 64;
#pragma unroll
      for (int c = 0; c < 4; ++c) gll16(a_base + c * (32 * KPAD) + ko, asd + c * 2048);
    }
    {
      const long kb = (long)ks * 64;
#pragma unroll
      for (int c = 0; c < 4; ++c) gll16(b_base + c * (32 * KB64) + kb, bsd + c * 2048);
    }
    __syncthreads();
#pragma unroll
    for (int ksub = 0; ksub < 2; ++ksub) {
      const int co = ((4 * ksub + kq) ^ swz) << 3;
      bf16x8 af[4], bfr[4];
#pragma unroll
      for (int i = 0; i < 4; ++i)
        af[i] = *(const bf16x8*)(As + (wr + 16 * i + row16) * 64 + co);
#pragma unroll
      for (int j = 0; j < 4; ++j)
        bfr[j] = *(const bf16x8*)(Bs + (wc + 16 * j + row16) * 64 + co);
#pragma unroll
      for (int i = 0; i < 4; ++i)
#pragma unroll
        for (int j = 0; j < 4; ++j)
          acc[i][j] = __builtin_amdgcn_mfma_f32_16x16x32_bf16(af[i], bfr[j], acc[i][j], 0, 0, 0);
    }
    __syncthreads();
  }
#pragma unroll
  for (int i = 0; i < 4; ++i)
#pragma unroll
    for (int j = 0; j < 4; ++j)
#pragma unroll
      for (int r = 0; r < 4; ++r) {
        long row = m0 + wr + 16 * i + rowg + r;
        int colj = n0 + wc + 16 * j + row16;
        int dv = agent_dir[row];
        float base = dir_gate[dv * G4 + colj];
        int u = colj & 255, g = colj >> 8;
        xg[row * G4 + u * 4 + g] = (bf16)(acc[i][j][r] + base);
      }
}

// ---------------- LSTM scan (R17 structural floor: ~1030 us) ----------
__global__ __launch_bounds__(1024)
void k_lstm(const bf16* __restrict__ xg, const unsigned char* __restrict__ wh8,
            const int* __restrict__ dones,
            const float* __restrict__ c0, const float* __restrict__ h0,
            bf16* __restrict__ ys, float* __restrict__ cfin, float* __restrict__ hfin) {
  __shared__ __align__(16) unsigned char wi8_lds[256 * WPITCH];
  __shared__ __align__(16) unsigned char wg8_lds[256 * WPITCH];
  __shared__ __align__(16) unsigned char h8_lds[2][16 * WPITCH];
  const int tid = threadIdx.x;
  const int w = tid >> 6, lane = tid & 63;
  const int col = lane & 15;
  const int kq = lane >> 4;
  const int k8 = kq * 8;
  const int rowg = kq * 4;
  const int b0 = blockIdx.x * 16;
  const int ju = 16 * w + col;

  for (int i = tid; i < 256 * 32; i += 1024) {
    int row = i >> 5, c = i & 31;
    *(long long*)(wi8_lds + row * WPITCH + c * 8) =
        *(const long long*)(wh8 + row * 256 + c * 8);
    *(long long*)(wg8_lds + row * WPITCH + c * 8) =
        *(const long long*)(wh8 + 2 * 65536 + row * 256 + c * 8);
  }
  for (int i = tid; i < 16 * HID; i += 1024) {
    int m = i >> 8, j = i & 255;
    h8_lds[0][m * WPITCH + j] = to_fp8(h0[(b0 + m) * HID + j]);
  }

  float creg[4], c0reg[4];
  unsigned char h0b8[4];
#pragma unroll
  for (int r = 0; r < 4; ++r) {
    float v = c0[(b0 + rowg + r) * HID + ju];
    creg[r] = v; c0reg[r] = v;
    h0b8[r] = to_fp8(h0[(b0 + rowg + r) * HID + ju]);
  }
  const unsigned char* wfp = wh8 + 1 * 65536 + ju * 256 + k8;
  const unsigned char* wop = wh8 + 3 * 65536 + ju * 256 + k8;

  int4 dnA = *(const int4*)(dones + b0 + rowg);
  bf16x4 xc[4];
  {
    const bf16* xb = xg + (long)(b0 + rowg) * G4 + ju * 4;
#pragma unroll
    for (int r = 0; r < 4; ++r)
      xc[r] = *(const bf16x4*)(xb + (long)r * G4);
  }
  long long bfr[4], bor[4];
#pragma unroll
  for (int c = 0; c < 3; ++c) {
    bfr[c] = *(const long long*)(wfp + c * 32);
    bor[c] = *(const long long*)(wop + c * 32);
  }
  __syncthreads();

  const unsigned char* hr = h8_lds[0];
  unsigned char* hw = (unsigned char*)h8_lds[1];

#pragma unroll 1
  for (int t = 0; t < T_DIM; ++t) {
    const int tn = (t + 1 < T_DIM) ? t + 1 : (T_DIM - 1);
    f32x4 acc[4];
    const f32x4 zero = {0.f, 0.f, 0.f, 0.f};
#pragma unroll
    for (int g = 0; g < 4; ++g) acc[g] = zero;

    int4 dnB;
#pragma unroll
    for (int ks = 0; ks < 8; ++ks) {
      {
        const int kn = (ks + 3) & 7, slot = (ks + 3) & 3;
        bfr[slot] = *(const long long*)(wfp + kn * 32);
        bor[slot] = *(const long long*)(wop + kn * 32);
      }
      long long a8 = *(const long long*)(hr + col * WPITCH + ks * 32 + k8);
      long long bi8 = *(const long long*)(wi8_lds + ju * WPITCH + ks * 32 + k8);
      long long bg8 = *(const long long*)(wg8_lds + ju * WPITCH + ks * 32 + k8);
      __builtin_amdgcn_s_setprio(1);
      acc[0] = __builtin_amdgcn_mfma_f32_16x16x32_fp8_fp8(a8, bi8, acc[0], 0, 0, 0);
      acc[1] = __builtin_amdgcn_mfma_f32_16x16x32_fp8_fp8(a8, bfr[ks & 3], acc[1], 0, 0, 0);
      acc[2] = __builtin_amdgcn_mfma_f32_16x16x32_fp8_fp8(a8, bg8, acc[2], 0, 0, 0);
      acc[3] = __builtin_amdgcn_mfma_f32_16x16x32_fp8_fp8(a8, bor[ks & 3], acc[3], 0, 0, 0);
      __builtin_amdgcn_s_setprio(0);
      if (ks == 2)
        dnB = *(const int4*)(dones + (long)tn * B_DIM + b0 + rowg);
    }

    int dc[4] = {dnA.x, dnA.y, dnA.z, dnA.w};
    int dx[4] = {dnB.x, dnB.y, dnB.z, dnB.w};
#pragma unroll
    for (int r = 0; r < 4; ++r) {
      float c_old = dc[r] ? c0reg[r] : creg[r];
      float gi = acc[0][r] + (float)xc[r][0];
      float gf = acc[1][r] + (float)xc[r][1];
      float gg = acc[2][r] + (float)xc[r][2];
      float go = acc[3][r] + (float)xc[r][3];
      float cn = sigm(gf) * c_old + sigm(gi) * tanh_(gg);
      float hn = sigm(go) * tanh_(cn);
      creg[r] = cn;
      int m = rowg + r;
      ys[((long)t * B_DIM + b0 + m) * HID + ju] = (bf16)hn;
      hw[m * WPITCH + ju] = dx[r] ? h0b8[r] : to_fp8(hn);
      if (t == T_DIM - 1) {
        cfin[(b0 + m) * HID + ju] = cn;
        hfin[(b0 + m) * HID + ju] = hn;
      }
    }
    {
      const bf16* xb = xg + (long)(tn * B_DIM + b0 + rowg) * G4 + ju * 4;
#pragma unroll
      for (int r = 0; r < 4; ++r)
        xc[r] = *(const bf16x4*)(xb + (long)r * G4);
    }
    dnA = dnB;
    bar_lds();
    { const unsigned char* tmp = hr; hr = hw; hw = (unsigned char*)tmp; }
  }
}

// ---------------- fused heads ----------------
#define H1PITCH 66
__global__ __launch_bounds__(256, 2)
void k_heads(const bf16* __restrict__ ys, const bf16* __restrict__ w0t,
             const float* __restrict__ a0b, const float* __restrict__ cr0b,
             const float* __restrict__ a1k, const float* __restrict__ a1b,
             const float* __restrict__ cr1k, const float* __restrict__ cr1b,
             float* __restrict__ logits, float* __restrict__ value) {
  __shared__ __align__(16) bf16 As[128 * 32];
  __shared__ __align__(16) bf16 Ws[64 * 264];
  __shared__ bf16 h1_lds[128 * H1PITCH];
  __shared__ float w2[32 * 8];
  const int tid = threadIdx.x, wave = tid >> 6, lane = tid & 63;
  const int row16 = lane & 15, k8 = (lane >> 4) * 8, rowg = (lane >> 4) * 4;
  const long m0 = (long)blockIdx.x * 128;
  for (int i = tid; i < 64 * 256; i += 256) {
    int n = i >> 8, k = i & 255;
    Ws[n * 264 + k] = w0t[i];
  }
  if (tid < 224) { int k = tid / 7, c = tid % 7; w2[k * 8 + c] = a1k[tid]; }
  else if (tid < 256) { int k = tid - 224; w2[k * 8 + 7] = cr1k[k]; }
  const bf16* a_src0 = ys + (m0 + tid / 4) * HID + (tid % 4) * 8;
  const bf16* a_src1 = ys + (m0 + 64 + tid / 4) * HID + (tid % 4) * 8;
  bf16* asd0 = As + wave * 512;
  bf16* asd1 = As + 2048 + wave * 512;
  f32x4 acc[2][4];
  const f32x4 zero = {0.f, 0.f, 0.f, 0.f};
#pragma unroll
  for (int i = 0; i < 2; ++i)
#pragma unroll
    for (int j = 0; j < 4; ++j) acc[i][j] = zero;
  for (int ks = 0; ks < 8; ++ks) {
    gll16(a_src0 + ks * 32, asd0);
    gll16(a_src1 + ks * 32, asd1);
    __syncthreads();
    bf16x8 bw[4];
#pragma unroll
    for (int j = 0; j < 4; ++j)
      bw[j] = *(const bf16x8*)(Ws + (16 * j + row16) * 264 + ks * 32 + k8);
#pragma unroll
    for (int i = 0; i < 2; ++i) {
      bf16x8 a = *(const bf16x8*)(As + (32 * wave + 16 * i + row16) * 32 + k8);
#pragma unroll
      for (int j = 0; j < 4; ++j)
        acc[i][j] = __builtin_amdgcn_mfma_f32_16x16x32_bf16(a, bw[j], acc[i][j], 0, 0, 0);
    }
    __syncthreads();
  }
#pragma unroll
  for (int i = 0; i < 2; ++i)
#pragma unroll
    for (int j = 0; j < 4; ++j)
#pragma unroll
      for (int r = 0; r < 4; ++r) {
        int rl = 32 * wave + 16 * i + rowg + r;
        int n = 16 * j + row16;
        float bias = (n < 32) ? a0b[n] : cr0b[n - 32];
        h1_lds[rl * H1PITCH + n] = (bf16)fmaxf(acc[i][j][r] + bias, 0.f);
      }
  __syncthreads();
  if (tid < 128) {
    const bf16* hp = h1_lds + tid * H1PITCH;
    float acc7[7];
#pragma unroll
    for (int c = 0; c < 7; ++c) acc7[c] = a1b[c];
    float accv = cr1b[0];
#pragma unroll 4
    for (int k = 0; k < 32; ++k) {
      float av = (float)hp[k];
      float cv = (float)hp[32 + k];
#pragma unroll
      for (int c = 0; c < 7; ++c) acc7[c] += av * w2[k * 8 + c];
      accv += cv * w2[k * 8 + 7];
    }
    long row = m0 + tid;
#pragma unroll
    for (int c = 0; c < 7; ++c) logits[row * 7 + c] = acc7[c];
    value[row] = accv;
  }
}

// ---------------- launch ----------------
extern "C" void kernel_launch(void* const* d_in, const int* in_sizes, int n_in,
                              void* d_out, int out_size, void* d_ws, size_t ws_size,
                              hipStream_t stream) {
  const float* image = (const float*)d_in[0];
  const int* agent_dir = (const int*)d_in[1];
  const int* dones = (const int*)d_in[2];
  const float* context = (const float*)d_in[3];
  const float* c0 = (const float*)d_in[4];
  const float* h0 = (const float*)d_in[5];
  const float* conv_k = (const float*)d_in[6];
  const float* conv_b = (const float*)d_in[7];
  const float* emb_k = (const float*)d_in[8];
  const float* emb_b = (const float*)d_in[9];
  const float* wi = (const float*)d_in[10];
  const float* wh = (const float*)d_in[11];
  const float* b_lstm = (const float*)d_in[12];
  const float* a0_k = (const float*)d_in[13];
  const float* a0_b = (const float*)d_in[14];
  const float* a1_k = (const float*)d_in[15];
  const float* a1_b = (const float*)d_in[16];
  const float* cr0_k = (const float*)d_in[17];
  const float* cr0_b = (const float*)d_in[18];
  const float* cr1_k = (const float*)d_in[19];
  const float* cr1_b = (const float*)d_in[20];

  char* ws = (char*)d_ws;
  const size_t off_conv = 0;                              // 419,430,400 (ys reuse)
  const size_t off_xg   = 419430400ULL;                   // 512 MB
  const size_t off_wiT  = off_xg  + 536870912ULL;         // 1024*896*2
  const size_t off_W0T  = off_wiT + 1835008ULL;
  const size_t off_dirg = off_W0T + 32768ULL;
  const size_t off_wh8  = off_dirg + 16384ULL;            // 4 gates x 64 KB
  const size_t off_ext  = off_wh8 + 262144ULL;
  const size_t total    = off_ext + 131072ULL;            // 958,578,688
  if (ws_size < total) return;

  bf16* conv_out = (bf16*)(ws + off_conv);
  bf16* xg       = (bf16*)(ws + off_xg);
  bf16* wiT      = (bf16*)(ws + off_wiT);
  bf16* W0T      = (bf16*)(ws + off_W0T);
  float* dir_gate = (float*)(ws + off_dirg);
  unsigned char* wh8 = (unsigned char*)(ws + off_wh8);
  bf16* ext = (bf16*)(ws + off_ext);
  bf16* ys = (bf16*)(ws + 0);               // reuses conv_out region (dead after GEMM)

  float* out_cfin = (float*)d_out;
  float* out_hfin = out_cfin + 262144;
  float* out_logits = out_cfin + 524288;
  float* out_value = out_cfin + 524288 + 1835008;

  k_wiT<<<1024, 256, 0, stream>>>(wi, wiT);
  k_ext<<<256, 256, 0, stream>>>(context, ext);
  k_W0T<<<64, 256, 0, stream>>>(a0_k, cr0_k, W0T);
  k_dirgate<<<4, 256, 0, stream>>>(wi, emb_k, emb_b, b_lstm, dir_gate);
  k_wh8<<<256, 256, 0, stream>>>(wh, wh8);
  k_conv<<<MROWS / CONV_ROWS, 256, 0, stream>>>(image, conv_k, conv_b, conv_out);
  k_gemm_xg<<<16384, 256, 0, stream>>>(conv_out, ext, wiT, dir_gate, agent_dir, xg);
  k_lstm<<<64, 1024, 0, stream>>>(xg, wh8, dones, c0, h0, ys, out_cfin, out_hfin);
  k_heads<<<2048, 256, 0, stream>>>(ys, W0T, a0_b, cr0_b, a1_k, a1_b, cr1_k, cr1_b,
                                    out_logits, out_value);
}

// Round 22
// 2253.015 us; speedup vs baseline: 2.0865x; 2.0865x over previous
//
#include <hip/hip_runtime.h>
#include <hip/hip_fp8.h>

typedef __bf16 bf16;
typedef __bf16 bf16x8 __attribute__((ext_vector_type(8)));
typedef __bf16 bf16x4 __attribute__((ext_vector_type(4)));
typedef float  f32x4  __attribute__((ext_vector_type(4)));

#define T_DIM 256
#define B_DIM 1024
#define HID   256
#define G4    1024
#define KIMG  784
#define KPAD  800
#define KB64  896
#define CTXD  64
#define MROWS (T_DIM*B_DIM)
#define WPITCH 264

__device__ __forceinline__ void gll16(const void* g, void* l) {
  __builtin_amdgcn_global_load_lds((const __attribute__((address_space(1))) void*)g,
                                   (__attribute__((address_space(3))) void*)l, 16, 0, 0);
}
__device__ __forceinline__ float sigm(float x) { return 1.f / (1.f + __expf(-x)); }
__device__ __forceinline__ float tanh_(float x) {
  x = fminf(fmaxf(x, -15.f), 15.f);
  float e = __expf(2.f * x);
  return (e - 1.f) / (e + 1.f);
}
__device__ __forceinline__ void bar_lds() {
  asm volatile("s_waitcnt lgkmcnt(0)\n\ts_barrier" ::: "memory");
}
__device__ __forceinline__ unsigned char to_fp8(float f) {
  __hip_fp8_e4m3 v(f);
  return *reinterpret_cast<unsigned char*>(&v);
}

// ---------------- prep kernels ----------------
// wiT[n][k], stride 896: k 0..63 = ctx weights (wi rows 789..852);
// 64..847 = img weights (wi rows 0..783); 848..895 = 0.
__global__ void k_wiT(const float* __restrict__ wi, bf16* __restrict__ wiT) {
  int n = blockIdx.x;
  for (int k = threadIdx.x; k < KB64; k += 256) {
    float v = 0.f;
    if (k < 64) v = wi[(long)(789 + k) * G4 + n];
    else if (k < 848) v = wi[(long)(k - 64) * G4 + n];
    wiT[(long)n * KB64 + k] = (bf16)v;
  }
}
__global__ void k_ext(const float* __restrict__ ctx, bf16* __restrict__ ext) {
  int idx = blockIdx.x * 256 + threadIdx.x;
  ext[idx] = (bf16)ctx[idx];
}
// fp8 e4m3 copies of ALL FOUR gate weight blocks, gate-major [g][n][k]
__global__ void k_wh8(const float* __restrict__ wh, unsigned char* __restrict__ wh8) {
  int n = blockIdx.x;
  int k = threadIdx.x;
#pragma unroll
  for (int g = 0; g < 4; ++g)
    wh8[g * 65536 + n * 256 + k] = to_fp8(wh[k * G4 + g * 256 + n]);
}
__global__ void k_W0T(const float* __restrict__ a0k, const float* __restrict__ cr0k,
                      bf16* __restrict__ w0t) {
  int n = blockIdx.x;
  int k = threadIdx.x;
  float v = (n < 32) ? a0k[k * 32 + n] : cr0k[k * 32 + (n - 32)];
  w0t[n * HID + k] = (bf16)v;
}
__global__ void k_dirgate(const float* __restrict__ wi, const float* __restrict__ emb_k,
                          const float* __restrict__ emb_b, const float* __restrict__ b_lstm,
                          float* __restrict__ dir_gate) {
  int d = blockIdx.x;
  for (int n = threadIdx.x; n < G4; n += 256) {
    float s = b_lstm[n];
#pragma unroll
    for (int j = 0; j < 5; ++j) s += (emb_k[d * 5 + j] + emb_b[j]) * wi[(KIMG + j) * G4 + n];
    dir_gate[d * G4 + n] = s;
  }
}

// ---------------- conv (R14 known-good scalar version) ----------------
#define CONV_ROWS 8
__global__ void k_conv(const float* __restrict__ img, const float* __restrict__ ck,
                       const float* __restrict__ cb, bf16* __restrict__ out) {
  __shared__ float s_img[CONV_ROWS * 243];
  __shared__ float s_k[432];
  __shared__ float s_b[16];
  long r0 = (long)blockIdx.x * CONV_ROWS;
  const float* src = img + r0 * 243;
  for (int i = threadIdx.x; i < CONV_ROWS * 243; i += 256) s_img[i] = src[i];
  for (int i = threadIdx.x; i < 432; i += 256) s_k[i] = ck[i];
  if (threadIdx.x < 16) s_b[threadIdx.x] = cb[threadIdx.x];
  __syncthreads();
  for (int idx = threadIdx.x; idx < CONV_ROWS * KPAD; idx += 256) {
    int r = idx / KPAD, c = idx % KPAD;
    float v = 0.f;
    if (c < KIMG) {
      int pix = c >> 4, ch = c & 15;
      int oy = pix / 7, ox = pix % 7;
      const float* ib = s_img + r * 243 + (oy * 9 + ox) * 3;
      v = s_b[ch];
#pragma unroll
      for (int ky = 0; ky < 3; ++ky)
#pragma unroll
        for (int kx = 0; kx < 3; ++kx)
#pragma unroll
          for (int cc = 0; cc < 3; ++cc)
            v += ib[(ky * 9 + kx) * 3 + cc] * s_k[((ky * 3 + kx) * 3 + cc) * 16 + ch];
      v = fmaxf(v, 0.f);
    }
    out[r0 * KPAD + idx] = (bf16)v;
  }
}

// ---------------- big GEMM (R18 known-good): 128x128, BK=64, swizzled ----
// A-cols: [0..63]=ext(ctx, row&1023) [64..847]=conv [848..895]=junk x zeros.
__global__ __launch_bounds__(256, 2)
void k_gemm_xg(const bf16* __restrict__ A, const bf16* __restrict__ ext,
               const bf16* __restrict__ Bt, const float* __restrict__ dir_gate,
               const int* __restrict__ agent_dir, bf16* __restrict__ xg) {
  __shared__ __align__(16) bf16 As[128 * 64];
  __shared__ __align__(16) bf16 Bs[128 * 64];
  const int bid = blockIdx.x;
  const int xcd = bid & 7, local = bid >> 3;
  const long m0 = (long)(xcd * 256 + (local >> 3)) * 128;
  const int n0 = (local & 7) * 128;
  const int tid = threadIdx.x, wave = tid >> 6, lane = tid & 63;
  const int row16 = lane & 15, kq = lane >> 4, rowg = kq * 4;
  const int wr = (wave >> 1) * 64, wc = (wave & 1) * 64;

  const int srow = 8 * wave + (lane >> 3);
  const int csrc8 = ((lane & 7) ^ (lane >> 3)) * 8;   // swizzled source col (elems)
  const bf16* a_base = A + (long)(m0 + srow) * KPAD + csrc8;
  const bf16* e_base = ext + (long)((m0 & 1023) + srow) * CTXD + csrc8;
  const bf16* b_base = Bt + (long)(n0 + srow) * KB64 + csrc8;
  bf16* asd = As + wave * 512;
  bf16* bsd = Bs + wave * 512;

  f32x4 acc[4][4];
  const f32x4 zero = {0.f, 0.f, 0.f, 0.f};
#pragma unroll
  for (int i = 0; i < 4; ++i)
#pragma unroll
    for (int j = 0; j < 4; ++j) acc[i][j] = zero;

  const int swz = row16 & 7;
  for (int ks = 0; ks < 14; ++ks) {
    if (ks == 0) {
#pragma unroll
      for (int c = 0; c < 4; ++c) gll16(e_base + c * (32 * CTXD), asd + c * 2048);
    } else {
      const long ko = (long)(ks - 1) * 64;
#pragma unroll
      for (int c = 0; c < 4; ++c) gll16(a_base + c * (32 * KPAD) + ko, asd + c * 2048);
    }
    {
      const long kb = (long)ks * 64;
#pragma unroll
      for (int c = 0; c < 4; ++c) gll16(b_base + c * (32 * KB64) + kb, bsd + c * 2048);
    }
    __syncthreads();
#pragma unroll
    for (int ksub = 0; ksub < 2; ++ksub) {
      const int co = ((4 * ksub + kq) ^ swz) << 3;
      bf16x8 af[4], bfr[4];
#pragma unroll
      for (int i = 0; i < 4; ++i)
        af[i] = *(const bf16x8*)(As + (wr + 16 * i + row16) * 64 + co);
#pragma unroll
      for (int j = 0; j < 4; ++j)
        bfr[j] = *(const bf16x8*)(Bs + (wc + 16 * j + row16) * 64 + co);
#pragma unroll
      for (int i = 0; i < 4; ++i)
#pragma unroll
        for (int j = 0; j < 4; ++j)
          acc[i][j] = __builtin_amdgcn_mfma_f32_16x16x32_bf16(af[i], bfr[j], acc[i][j], 0, 0, 0);
    }
    __syncthreads();
  }
#pragma unroll
  for (int i = 0; i < 4; ++i)
#pragma unroll
    for (int j = 0; j < 4; ++j)
#pragma unroll
      for (int r = 0; r < 4; ++r) {
        long row = m0 + wr + 16 * i + rowg + r;
        int colj = n0 + wc + 16 * j + row16;
        int dv = agent_dir[row];
        float base = dir_gate[dv * G4 + colj];
        int u = colj & 255, g = colj >> 8;
        xg[row * G4 + u * 4 + g] = (bf16)(acc[i][j][r] + base);
      }
}

// ---------------- LSTM scan (R17 structural floor: ~1030 us) ----------
__global__ __launch_bounds__(1024)
void k_lstm(const bf16* __restrict__ xg, const unsigned char* __restrict__ wh8,
            const int* __restrict__ dones,
            const float* __restrict__ c0, const float* __restrict__ h0,
            bf16* __restrict__ ys, float* __restrict__ cfin, float* __restrict__ hfin) {
  __shared__ __align__(16) unsigned char wi8_lds[256 * WPITCH];
  __shared__ __align__(16) unsigned char wg8_lds[256 * WPITCH];
  __shared__ __align__(16) unsigned char h8_lds[2][16 * WPITCH];
  const int tid = threadIdx.x;
  const int w = tid >> 6, lane = tid & 63;
  const int col = lane & 15;
  const int kq = lane >> 4;
  const int k8 = kq * 8;
  const int rowg = kq * 4;
  const int b0 = blockIdx.x * 16;
  const int ju = 16 * w + col;

  for (int i = tid; i < 256 * 32; i += 1024) {
    int row = i >> 5, c = i & 31;
    *(long long*)(wi8_lds + row * WPITCH + c * 8) =
        *(const long long*)(wh8 + row * 256 + c * 8);
    *(long long*)(wg8_lds + row * WPITCH + c * 8) =
        *(const long long*)(wh8 + 2 * 65536 + row * 256 + c * 8);
  }
  for (int i = tid; i < 16 * HID; i += 1024) {
    int m = i >> 8, j = i & 255;
    h8_lds[0][m * WPITCH + j] = to_fp8(h0[(b0 + m) * HID + j]);
  }

  float creg[4], c0reg[4];
  unsigned char h0b8[4];
#pragma unroll
  for (int r = 0; r < 4; ++r) {
    float v = c0[(b0 + rowg + r) * HID + ju];
    creg[r] = v; c0reg[r] = v;
    h0b8[r] = to_fp8(h0[(b0 + rowg + r) * HID + ju]);
  }
  const unsigned char* wfp = wh8 + 1 * 65536 + ju * 256 + k8;
  const unsigned char* wop = wh8 + 3 * 65536 + ju * 256 + k8;

  int4 dnA = *(const int4*)(dones + b0 + rowg);
  bf16x4 xc[4];
  {
    const bf16* xb = xg + (long)(b0 + rowg) * G4 + ju * 4;
#pragma unroll
    for (int r = 0; r < 4; ++r)
      xc[r] = *(const bf16x4*)(xb + (long)r * G4);
  }
  long long bfr[4], bor[4];
#pragma unroll
  for (int c = 0; c < 3; ++c) {
    bfr[c] = *(const long long*)(wfp + c * 32);
    bor[c] = *(const long long*)(wop + c * 32);
  }
  __syncthreads();

  const unsigned char* hr = h8_lds[0];
  unsigned char* hw = (unsigned char*)h8_lds[1];

#pragma unroll 1
  for (int t = 0; t < T_DIM; ++t) {
    const int tn = (t + 1 < T_DIM) ? t + 1 : (T_DIM - 1);
    f32x4 acc[4];
    const f32x4 zero = {0.f, 0.f, 0.f, 0.f};
#pragma unroll
    for (int g = 0; g < 4; ++g) acc[g] = zero;

    int4 dnB;
#pragma unroll
    for (int ks = 0; ks < 8; ++ks) {
      {
        const int kn = (ks + 3) & 7, slot = (ks + 3) & 3;
        bfr[slot] = *(const long long*)(wfp + kn * 32);
        bor[slot] = *(const long long*)(wop + kn * 32);
      }
      long long a8 = *(const long long*)(hr + col * WPITCH + ks * 32 + k8);
      long long bi8 = *(const long long*)(wi8_lds + ju * WPITCH + ks * 32 + k8);
      long long bg8 = *(const long long*)(wg8_lds + ju * WPITCH + ks * 32 + k8);
      __builtin_amdgcn_s_setprio(1);
      acc[0] = __builtin_amdgcn_mfma_f32_16x16x32_fp8_fp8(a8, bi8, acc[0], 0, 0, 0);
      acc[1] = __builtin_amdgcn_mfma_f32_16x16x32_fp8_fp8(a8, bfr[ks & 3], acc[1], 0, 0, 0);
      acc[2] = __builtin_amdgcn_mfma_f32_16x16x32_fp8_fp8(a8, bg8, acc[2], 0, 0, 0);
      acc[3] = __builtin_amdgcn_mfma_f32_16x16x32_fp8_fp8(a8, bor[ks & 3], acc[3], 0, 0, 0);
      __builtin_amdgcn_s_setprio(0);
      if (ks == 2)
        dnB = *(const int4*)(dones + (long)tn * B_DIM + b0 + rowg);
    }

    int dc[4] = {dnA.x, dnA.y, dnA.z, dnA.w};
    int dx[4] = {dnB.x, dnB.y, dnB.z, dnB.w};
#pragma unroll
    for (int r = 0; r < 4; ++r) {
      float c_old = dc[r] ? c0reg[r] : creg[r];
      float gi = acc[0][r] + (float)xc[r][0];
      float gf = acc[1][r] + (float)xc[r][1];
      float gg = acc[2][r] + (float)xc[r][2];
      float go = acc[3][r] + (float)xc[r][3];
      float cn = sigm(gf) * c_old + sigm(gi) * tanh_(gg);
      float hn = sigm(go) * tanh_(cn);
      creg[r] = cn;
      int m = rowg + r;
      ys[((long)t * B_DIM + b0 + m) * HID + ju] = (bf16)hn;
      hw[m * WPITCH + ju] = dx[r] ? h0b8[r] : to_fp8(hn);
      if (t == T_DIM - 1) {
        cfin[(b0 + m) * HID + ju] = cn;
        hfin[(b0 + m) * HID + ju] = hn;
      }
    }
    {
      const bf16* xb = xg + (long)(tn * B_DIM + b0 + rowg) * G4 + ju * 4;
#pragma unroll
      for (int r = 0; r < 4; ++r)
        xc[r] = *(const bf16x4*)(xb + (long)r * G4);
    }
    dnA = dnB;
    bar_lds();
    { const unsigned char* tmp = hr; hr = hw; hw = (unsigned char*)tmp; }
  }
}

// ---------------- fused heads ----------------
#define H1PITCH 66
__global__ __launch_bounds__(256, 2)
void k_heads(const bf16* __restrict__ ys, const bf16* __restrict__ w0t,
             const float* __restrict__ a0b, const float* __restrict__ cr0b,
             const float* __restrict__ a1k, const float* __restrict__ a1b,
             const float* __restrict__ cr1k, const float* __restrict__ cr1b,
             float* __restrict__ logits, float* __restrict__ value) {
  __shared__ __align__(16) bf16 As[128 * 32];
  __shared__ __align__(16) bf16 Ws[64 * 264];
  __shared__ bf16 h1_lds[128 * H1PITCH];
  __shared__ float w2[32 * 8];
  const int tid = threadIdx.x, wave = tid >> 6, lane = tid & 63;
  const int row16 = lane & 15, k8 = (lane >> 4) * 8, rowg = (lane >> 4) * 4;
  const long m0 = (long)blockIdx.x * 128;
  for (int i = tid; i < 64 * 256; i += 256) {
    int n = i >> 8, k = i & 255;
    Ws[n * 264 + k] = w0t[i];
  }
  if (tid < 224) { int k = tid / 7, c = tid % 7; w2[k * 8 + c] = a1k[tid]; }
  else if (tid < 256) { int k = tid - 224; w2[k * 8 + 7] = cr1k[k]; }
  const bf16* a_src0 = ys + (m0 + tid / 4) * HID + (tid % 4) * 8;
  const bf16* a_src1 = ys + (m0 + 64 + tid / 4) * HID + (tid % 4) * 8;
  bf16* asd0 = As + wave * 512;
  bf16* asd1 = As + 2048 + wave * 512;
  f32x4 acc[2][4];
  const f32x4 zero = {0.f, 0.f, 0.f, 0.f};
#pragma unroll
  for (int i = 0; i < 2; ++i)
#pragma unroll
    for (int j = 0; j < 4; ++j) acc[i][j] = zero;
  for (int ks = 0; ks < 8; ++ks) {
    gll16(a_src0 + ks * 32, asd0);
    gll16(a_src1 + ks * 32, asd1);
    __syncthreads();
    bf16x8 bw[4];
#pragma unroll
    for (int j = 0; j < 4; ++j)
      bw[j] = *(const bf16x8*)(Ws + (16 * j + row16) * 264 + ks * 32 + k8);
#pragma unroll
    for (int i = 0; i < 2; ++i) {
      bf16x8 a = *(const bf16x8*)(As + (32 * wave + 16 * i + row16) * 32 + k8);
#pragma unroll
      for (int j = 0; j < 4; ++j)
        acc[i][j] = __builtin_amdgcn_mfma_f32_16x16x32_bf16(a, bw[j], acc[i][j], 0, 0, 0);
    }
    __syncthreads();
  }
#pragma unroll
  for (int i = 0; i < 2; ++i)
#pragma unroll
    for (int j = 0; j < 4; ++j)
#pragma unroll
      for (int r = 0; r < 4; ++r) {
        int rl = 32 * wave + 16 * i + rowg + r;
        int n = 16 * j + row16;
        float bias = (n < 32) ? a0b[n] : cr0b[n - 32];
        h1_lds[rl * H1PITCH + n] = (bf16)fmaxf(acc[i][j][r] + bias, 0.f);
      }
  __syncthreads();
  if (tid < 128) {
    const bf16* hp = h1_lds + tid * H1PITCH;
    float acc7[7];
#pragma unroll
    for (int c = 0; c < 7; ++c) acc7[c] = a1b[c];
    float accv = cr1b[0];
#pragma unroll 4
    for (int k = 0; k < 32; ++k) {
      float av = (float)hp[k];
      float cv = (float)hp[32 + k];
#pragma unroll
      for (int c = 0; c < 7; ++c) acc7[c] += av * w2[k * 8 + c];
      accv += cv * w2[k * 8 + 7];
    }
    long row = m0 + tid;
#pragma unroll
    for (int c = 0; c < 7; ++c) logits[row * 7 + c] = acc7[c];
    value[row] = accv;
  }
}

// ---------------- launch ----------------
extern "C" void kernel_launch(void* const* d_in, const int* in_sizes, int n_in,
                              void* d_out, int out_size, void* d_ws, size_t ws_size,
                              hipStream_t stream) {
  const float* image = (const float*)d_in[0];
  const int* agent_dir = (const int*)d_in[1];
  const int* dones = (const int*)d_in[2];
  const float* context = (const float*)d_in[3];
  const float* c0 = (const float*)d_in[4];
  const float* h0 = (const float*)d_in[5];
  const float* conv_k = (const float*)d_in[6];
  const float* conv_b = (const float*)d_in[7];
  const float* emb_k = (const float*)d_in[8];
  const float* emb_b = (const float*)d_in[9];
  const float* wi = (const float*)d_in[10];
  const float* wh = (const float*)d_in[11];
  const float* b_lstm = (const float*)d_in[12];
  const float* a0_k = (const float*)d_in[13];
  const float* a0_b = (const float*)d_in[14];
  const float* a1_k = (const float*)d_in[15];
  const float* a1_b = (const float*)d_in[16];
  const float* cr0_k = (const float*)d_in[17];
  const float* cr0_b = (const float*)d_in[18];
  const float* cr1_k = (const float*)d_in[19];
  const float* cr1_b = (const float*)d_in[20];

  char* ws = (char*)d_ws;
  const size_t off_conv = 0;                              // 419,430,400 (ys reuse)
  const size_t off_xg   = 419430400ULL;                   // 512 MB
  const size_t off_wiT  = off_xg  + 536870912ULL;         // 1024*896*2
  const size_t off_W0T  = off_wiT + 1835008ULL;
  const size_t off_dirg = off_W0T + 32768ULL;
  const size_t off_wh8  = off_dirg + 16384ULL;            // 4 gates x 64 KB
  const size_t off_ext  = off_wh8 + 262144ULL;
  const size_t total    = off_ext + 131072ULL;            // 958,578,688
  if (ws_size < total) return;

  bf16* conv_out = (bf16*)(ws + off_conv);
  bf16* xg       = (bf16*)(ws + off_xg);
  bf16* wiT      = (bf16*)(ws + off_wiT);
  bf16* W0T      = (bf16*)(ws + off_W0T);
  float* dir_gate = (float*)(ws + off_dirg);
  unsigned char* wh8 = (unsigned char*)(ws + off_wh8);
  bf16* ext = (bf16*)(ws + off_ext);
  bf16* ys = (bf16*)(ws + 0);               // reuses conv_out region (dead after GEMM)

  float* out_cfin = (float*)d_out;
  float* out_hfin = out_cfin + 262144;
  float* out_logits = out_cfin + 524288;
  float* out_value = out_cfin + 524288 + 1835008;

  k_wiT<<<1024, 256, 0, stream>>>(wi, wiT);
  k_ext<<<256, 256, 0, stream>>>(context, ext);
  k_W0T<<<64, 256, 0, stream>>>(a0_k, cr0_k, W0T);
  k_dirgate<<<4, 256, 0, stream>>>(wi, emb_k, emb_b, b_lstm, dir_gate);
  k_wh8<<<256, 256, 0, stream>>>(wh, wh8);
  k_conv<<<MROWS / CONV_ROWS, 256, 0, stream>>>(image, conv_k, conv_b, conv_out);
  k_gemm_xg<<<16384, 256, 0, stream>>>(conv_out, ext, wiT, dir_gate, agent_dir, xg);
  k_lstm<<<64, 1024, 0, stream>>>(xg, wh8, dones, c0, h0, ys, out_cfin, out_hfin);
  k_heads<<<2048, 256, 0, stream>>>(ys, W0T, a0_b, cr0_b, a1_k, a1_b, cr1_k, cr1_b,
                                    out_logits, out_value);
}